// Round 14
// baseline (218.055 us; speedup 1.0000x reference)
//
#include <hip/hip_runtime.h>
#include <hip/hip_bf16.h>

#define BB 4
#define NN 200
#define HH 300
#define NCH 10            // k-steps of 32 (K padded to 320)
#define GF 20             // g-frags of 16 (full G padded to 320)
#define GHF 10            // g-frags per g-half
#define WS_BP    0
#define WS_BPF   204800
#define WS_VX    409600
#define WS_EBF   1369600
#define WS_NEED  (WS_EBF + 102400000ull)

typedef __attribute__((ext_vector_type(8))) short short8;
typedef __attribute__((ext_vector_type(4))) float float4v;

static __device__ __forceinline__ ushort f2bf(float x) {
    union { float f; uint u; } v; v.f = x;
    uint r = v.u + 0x7FFFu + ((v.u >> 16) & 1u);  // RNE
    return (ushort)(r >> 16);
}

static __device__ __forceinline__ short8 pack8_cvt(float4v a, float4v b) {
    uint u0, u1, u2, u3;
    asm("v_cvt_pk_bf16_f32 %0, %1, %2" : "=v"(u0) : "v"(a[0]), "v"(a[1]));
    asm("v_cvt_pk_bf16_f32 %0, %1, %2" : "=v"(u1) : "v"(a[2]), "v"(a[3]));
    asm("v_cvt_pk_bf16_f32 %0, %1, %2" : "=v"(u2) : "v"(b[0]), "v"(b[1]));
    asm("v_cvt_pk_bf16_f32 %0, %1, %2" : "=v"(u3) : "v"(b[2]), "v"(b[3]));
    union { uint u[4]; short8 s; } r;
    r.u[0] = u0; r.u[1] = u1; r.u[2] = u2; r.u[3] = u3;
    return r.s;
}

static __device__ __forceinline__ void gload_lds16(const void* g, void* l) {
    __builtin_amdgcn_global_load_lds(
        (const __attribute__((address_space(1))) unsigned int*)g,
        (__attribute__((address_space(3))) unsigned int*)l, 16, 0, 0);
}

// ---- U_w packers ----
__global__ void pack_u_gh(const float* __restrict__ Uw, ushort* __restrict__ Bp) {
    int idx = blockIdx.x * 256 + threadIdx.x;
    if (idx >= 2 * NCH * GHF * 64) return;
    int lane = idx & 63;
    int rem = idx >> 6;
    int fh = rem % GHF;
    int ks = (rem / GHF) % NCH;
    int gh = rem / (GHF * NCH);
    int g = (gh * GHF + fh) * 16 + (lane & 15);
    int h0 = ks * 32 + (lane >> 4) * 8;
    ushort v[8];
#pragma unroll
    for (int j = 0; j < 8; ++j) {
        int h = h0 + j;
        v[j] = (g < HH && h < HH) ? f2bf(Uw[g * HH + h]) : (ushort)0;
    }
    *reinterpret_cast<short8*>(Bp + (size_t)idx * 8) = *reinterpret_cast<const short8*>(v);
}

__global__ void pack_u_full(const float* __restrict__ Uw, ushort* __restrict__ Bp) {
    int idx = blockIdx.x * 256 + threadIdx.x;
    if (idx >= NCH * GF * 64) return;
    int lane = idx & 63;
    int kg = idx >> 6;
    int gf = kg % GF, ks = kg / GF;
    int g = gf * 16 + (lane & 15);
    int h0 = ks * 32 + (lane >> 4) * 8;
    ushort v[8];
#pragma unroll
    for (int j = 0; j < 8; ++j) {
        int h = h0 + j;
        v[j] = (g < HH && h < HH) ? f2bf(Uw[g * HH + h]) : (ushort)0;
    }
    *reinterpret_cast<short8*>(Bp + (size_t)idx * 8) = *reinterpret_cast<const short8*>(v);
}

// Vx[b,n,g] = x@Vw^T + Vb + 0.5*Ub  (Ub folded)
__global__ void vx_kernel(const float* __restrict__ x, const float* __restrict__ Vw,
                          const float* __restrict__ Vb, const float* __restrict__ Ub,
                          float* __restrict__ Vx) {
    __shared__ float xs[HH];
    int row = blockIdx.x;
    const float* xr = x + (size_t)row * HH;
    for (int h = threadIdx.x; h < HH; h += 256) xs[h] = xr[h];
    __syncthreads();
    for (int g = threadIdx.x; g < HH; g += 256) {
        const float4* wr = reinterpret_cast<const float4*>(Vw + (size_t)g * HH);
        const float4* xv = reinterpret_cast<const float4*>(xs);
        float s0 = 0.f, s1 = 0.f, s2 = 0.f, s3 = 0.f;
#pragma unroll 5
        for (int k = 0; k < HH / 4; ++k) {
            float4 w = wr[k];
            float4 xx = xv[k];
            s0 += w.x * xx.x; s1 += w.y * xx.y; s2 += w.z * xx.z; s3 += w.w * xx.w;
        }
        Vx[(size_t)row * HH + g] = Vb[g] + 0.5f * Ub[g] + s0 + s1 + s2 + s3;
    }
}

// ---- PASS 1 (LDS transpose): both global sides fully coalesced ----
// Block = one 32-row tile. Read 38.4 KB contiguous f32 -> cvt -> LDS [32][328];
// then write 20 KB contiguous frag units (unit = (ks*2+half)*64+lane -> 16B).
__global__ void pack_e(const float* __restrict__ e, ushort* __restrict__ ebf) {
    __shared__ __align__(16) ushort T[32][328];   // 656B row stride (16B-aligned, bank-friendly)
    const int t = blockIdx.x;       // 0..4999
    const int tid = threadIdx.x;    // 256

    // zero pad cols [300,328)
    for (int i = tid; i < 32 * 14; i += 256) {
        int row = i / 14, c = 300 + (i % 14) * 2;
        *reinterpret_cast<uint*>(&T[row][c]) = 0u;
    }
    // contiguous read + cvt + LDS write
    const float* src = e + (size_t)t * 32 * HH;
#pragma unroll
    for (int i = 0; i < 10; ++i) {
        int f4 = tid + i * 256;                  // 0..2399
        if (f4 < 2400) {
            int row = f4 / 75, c = (f4 - row * 75) * 4;
            float4v v = *reinterpret_cast<const float4v*>(src + f4 * 4);
            uint u0, u1;
            asm("v_cvt_pk_bf16_f32 %0, %1, %2" : "=v"(u0) : "v"(v[0]), "v"(v[1]));
            asm("v_cvt_pk_bf16_f32 %0, %1, %2" : "=v"(u1) : "v"(v[2]), "v"(v[3]));
            uint2 wv; wv.x = u0; wv.y = u1;
            *reinterpret_cast<uint2*>(&T[row][c]) = wv;
        }
    }
    __syncthreads();
    // contiguous frag-unit write
    ushort* dst = ebf + (size_t)t * 10240;
#pragma unroll
    for (int rr = 0; rr < 5; ++rr) {
        int u = tid + rr * 256;                  // 0..1279
        int lane = u & 63;
        int kh = u >> 6;                         // ks*2 + half
        int half = kh & 1, ks = kh >> 1;
        int row = half * 16 + (lane & 15);
        int c = ks * 32 + (lane >> 4) * 8;       // <= 312, pad covers >=300
        short8 wv = *reinterpret_cast<const short8*>(&T[row][c]);
        *reinterpret_cast<short8*>(dst + (size_t)u * 8) = wv;
    }
}

// ---- PASS 2 (free-run, zero LDS, zero barriers) ----
// Block = 512 thr / 8 waves on 64 rows: wave w -> gh = w>>2, rowgrp = w&3
// (both g-halves of the same rows in one block -> write locality).
// A: 16B/lane coalesced stream from ebf. B: direct from L2 (1KB/wave-instr).
__launch_bounds__(512, 2)
__global__ void gemm3(const ushort* __restrict__ ebf, const ushort* __restrict__ Bp,
                      const float* __restrict__ Vx, float* __restrict__ out) {
    const int tid = threadIdx.x;
    const int lane = tid & 63, w = tid >> 6;
    const int gh = w >> 2, rowgrp = w & 3;
    const int r = lane & 15, q = lane >> 4;
    const int mb = blockIdx.x;            // 0..2499
    const int m0 = mb * 64;
    const int tile = mb * 2 + (rowgrp >> 1);
    const int half = rowgrp & 1;

    // A frag stream base (ushort units): tile*10240 + (ks*2+half)*512 + lane*8
    const ushort* abase = ebf + (size_t)tile * 10240 + half * 512 + lane * 8;
    // B base for this g-half: gh*51200 + ks*5120 + f*512 + lane*8
    const ushort* bbase = Bp + (size_t)gh * 51200 + lane * 8;

    float4v acc[GHF];
#pragma unroll
    for (int f = 0; f < GHF; ++f) acc[f] = (float4v){0.f, 0.f, 0.f, 0.f};

#pragma unroll
    for (int ks = 0; ks < NCH; ++ks) {
        short8 fa = *reinterpret_cast<const short8*>(abase + ks * 1024);
        const ushort* bk = bbase + ks * 5120;
#pragma unroll
        for (int f = 0; f < GHF; ++f) {
            short8 bf = *reinterpret_cast<const short8*>(bk + f * 512);
            acc[f] = __builtin_amdgcn_mfma_f32_16x16x32_bf16(bf, fa, acc[f], 0, 0, 0);
        }
    }

    // epilogue: out[m][g] = acc + Vx'[i][g] + Vx'[j][g]  (Ub folded in Vx')
    {
        const int m = m0 + rowgrp * 16 + r;
        int j = m % NN;
        int ti = m / NN;
        int b = ti / NN;
        const float* vi = Vx + (size_t)ti * HH;
        const float* vj = Vx + (size_t)(b * NN + j) * HH;
        float* orow = out + (size_t)m * HH;
        const int gb = gh * (GHF * 16);
#pragma unroll
        for (int f = 0; f < GHF; ++f) {
            int g0 = gb + f * 16 + q * 4;
            if (g0 + 4 <= HH) {
                float4v vi4 = *reinterpret_cast<const float4v*>(vi + g0);
                float4v vj4 = *reinterpret_cast<const float4v*>(vj + g0);
                *reinterpret_cast<float4v*>(orow + g0) = acc[f] + vi4 + vj4;
            }
        }
    }
}

// ---- FALLBACK (R11, proven): used only if workspace is too small ----
__launch_bounds__(512, 2)
__global__ void gemm_fb(const float* __restrict__ e, const ushort* __restrict__ Bp,
                        const float* __restrict__ Vx, float* __restrict__ out) {
    __shared__ __align__(16) char SMEM[147456];
    const int tid = threadIdx.x;
    const int w = tid >> 6, l = tid & 63;
    const int r = l & 15, q = l >> 4;
    const int m0 = blockIdx.x * 128;

#define AFB(P_) (SMEM + (P_) * 32768)
#define BFB(P_) (SMEM + 65536 + (P_) * 40960)
#define WAITV(N_) asm volatile("s_waitcnt vmcnt(" #N_ ")" ::: "memory")
#define BAR() do {                                                   \
        __builtin_amdgcn_sched_barrier(0);                           \
        asm volatile("s_waitcnt lgkmcnt(0)" ::: "memory");           \
        __builtin_amdgcn_sched_barrier(0);                           \
        __builtin_amdgcn_s_barrier();                                \
        __builtin_amdgcn_sched_barrier(0);                           \
    } while (0)
#define STAGE_A(KC_, P_) do {                                                   \
        _Pragma("unroll")                                                       \
        for (int rd_ = 0; rd_ < 4; ++rd_) {                                     \
            int row_ = rd_ * 32 + w * 4 + (l >> 4);                             \
            int ucl_ = (l & 15) ^ (row_ & 15);                                  \
            const char* src_ = (const char*)(e + (size_t)(m0 + row_) * HH)      \
                               + (KC_) * 256 + ucl_ * 16;                       \
            if ((KC_) == 4 && ucl_ >= 11) src_ = (const char*)e;                \
            gload_lds16(src_, AFB(P_) + rd_ * 8192 + w * 1024 + l * 16);        \
        }                                                                       \
    } while (0)
#define STAGE_B(KC_, P_) do {                                                   \
        const char* bs_ = (const char*)Bp + (size_t)(KC_) * 40960;              \
        char* bd_ = BFB(P_);                                                    \
        _Pragma("unroll")                                                       \
        for (int rd_ = 0; rd_ < 5; ++rd_)                                       \
            gload_lds16(bs_ + rd_ * 8192 + tid * 16, bd_ + rd_ * 8192 + tid * 16); \
    } while (0)

    float4v acc[GF];
#pragma unroll
    for (int f = 0; f < GF; ++f) acc[f] = (float4v){0.f, 0.f, 0.f, 0.f};

#define COMPUTE(P_) do {                                                        \
        const char* ab_ = AFB(P_) + (w * 16 + r) * 256;                         \
        const ushort* bb_ = (const ushort*)BFB(P_);                             \
        _Pragma("unroll")                                                       \
        for (int s_ = 0; s_ < 2; ++s_) {                                        \
            int u0_ = (s_ * 8 + 2 * q) ^ r;                                     \
            int u1_ = (s_ * 8 + 2 * q + 1) ^ r;                                 \
            float4v fa0_ = *reinterpret_cast<const float4v*>(ab_ + u0_ * 16);   \
            float4v fa1_ = *reinterpret_cast<const float4v*>(ab_ + u1_ * 16);   \
            short8 fa_ = pack8_cvt(fa0_, fa1_);                                 \
            const ushort* bs_ = bb_ + s_ * (GF * 512) + l * 8;                  \
            _Pragma("unroll")                                                   \
            for (int f_ = 0; f_ < GF; ++f_) {                                   \
                short8 bfr_ = *reinterpret_cast<const short8*>(bs_ + f_ * 512); \
                acc[f_] = __builtin_amdgcn_mfma_f32_16x16x32_bf16(bfr_, fa_, acc[f_], 0, 0, 0); \
            }                                                                   \
        }                                                                       \
    } while (0)

    STAGE_A(0, 0); STAGE_B(0, 0);
    STAGE_A(1, 1); STAGE_B(1, 1);
    WAITV(9); BAR();
    COMPUTE(0); BAR(); STAGE_A(2, 0); STAGE_B(2, 0); WAITV(9); BAR();
    COMPUTE(1); BAR(); STAGE_A(3, 1); STAGE_B(3, 1); WAITV(9); BAR();
    COMPUTE(0); BAR(); STAGE_A(4, 0); STAGE_B(4, 0); WAITV(9); BAR();
    COMPUTE(1); BAR(); WAITV(0); BAR();
    COMPUTE(0);

    asm volatile("s_waitcnt lgkmcnt(0)" ::: "memory");
    __builtin_amdgcn_s_barrier();
    __builtin_amdgcn_sched_barrier(0);
    char* ep = SMEM + w * 10496;
    const int mbase = m0 + w * 16;
#pragma unroll
    for (int gh2 = 0; gh2 < 2; ++gh2) {
        if (gh2) { asm volatile("s_waitcnt lgkmcnt(0)" ::: "memory"); __builtin_amdgcn_sched_barrier(0); }
#pragma unroll
        for (int ff = 0; ff < 10; ++ff) {
            int f = gh2 * 10 + ff;
            if (f < 19)
                *reinterpret_cast<float4v*>(ep + r * 656 + ff * 64 + q * 16) = acc[f];
        }
        asm volatile("s_waitcnt lgkmcnt(0)" ::: "memory");
        __builtin_amdgcn_sched_barrier(0);
        const int nl = gh2 ? 35 : 40;
#pragma unroll 4
        for (int rr = 0; rr < 16; ++rr) {
            if (l < nl) {
                float4v v = *reinterpret_cast<const float4v*>(ep + rr * 656 + l * 16);
                int m = mbase + rr;
                int j = m % NN;
                int ti = m / NN;
                int b = ti / NN;
                int g0 = gh2 * 160 + l * 4;
                float4v vi4 = *reinterpret_cast<const float4v*>(Vx + (size_t)ti * HH + g0);
                float4v vj4 = *reinterpret_cast<const float4v*>(Vx + (size_t)(b * NN + j) * HH + g0);
                *reinterpret_cast<float4v*>(out + (size_t)m * HH + g0) = v + vi4 + vj4;
            }
        }
    }
#undef COMPUTE
#undef STAGE_A
#undef STAGE_B
#undef BAR
#undef WAITV
#undef AFB
#undef BFB
}

extern "C" void kernel_launch(void* const* d_in, const int* in_sizes, int n_in,
                              void* d_out, int out_size, void* d_ws, size_t ws_size,
                              hipStream_t stream) {
    const float* x  = (const float*)d_in[0];
    const float* e  = (const float*)d_in[1];
    const float* Uw = (const float*)d_in[2];
    const float* Ub = (const float*)d_in[3];
    const float* Vw = (const float*)d_in[4];
    const float* Vb = (const float*)d_in[5];
    float* out = (float*)d_out;

    ushort* Bp  = (ushort*)((char*)d_ws + WS_BP);    // g-half-major pack
    ushort* BpF = (ushort*)((char*)d_ws + WS_BPF);   // ks-major full-G pack (fallback)
    float*  Vx  = (float*)((char*)d_ws + WS_VX);
    ushort* ebf = (ushort*)((char*)d_ws + WS_EBF);   // 102.4 MB bf16 frag-packed e

    vx_kernel<<<BB * NN, 256, 0, stream>>>(x, Vw, Vb, Ub, Vx);

    if (ws_size >= WS_NEED) {
        pack_u_gh<<<50, 256, 0, stream>>>(Uw, Bp);
        pack_e<<<5000, 256, 0, stream>>>(e, ebf);
        gemm3<<<2500, 512, 0, stream>>>(ebf, Bp, Vx, out);
    } else {
        pack_u_full<<<50, 256, 0, stream>>>(Uw, BpF);
        gemm_fb<<<1250, 512, 0, stream>>>(e, BpF, Vx, out);
    }
}

// Round 15
// 185.688 us; speedup vs baseline: 1.1743x; 1.1743x over previous
//
#include <hip/hip_runtime.h>
#include <hip/hip_bf16.h>

#define BB 4
#define NN 200
#define HH 300
#define NCH 10            // k-chunks of 32 (K padded to 320)
#define GHF 10            // g-frags of 16 per g-half (G padded to 320)
#define BM 64             // rows per block

typedef __attribute__((ext_vector_type(8))) short short8;
typedef __attribute__((ext_vector_type(4))) float float4v;

static __device__ __forceinline__ ushort f2bf(float x) {
    union { float f; uint u; } v; v.f = x;
    uint r = v.u + 0x7FFFu + ((v.u >> 16) & 1u);  // RNE
    return (ushort)(r >> 16);
}

// 8 f32 -> 8 bf16 (RNE) via v_cvt_pk_bf16_f32
static __device__ __forceinline__ short8 pack8_cvt(float4v a, float4v b) {
    uint u0, u1, u2, u3;
    asm("v_cvt_pk_bf16_f32 %0, %1, %2" : "=v"(u0) : "v"(a[0]), "v"(a[1]));
    asm("v_cvt_pk_bf16_f32 %0, %1, %2" : "=v"(u1) : "v"(a[2]), "v"(a[3]));
    asm("v_cvt_pk_bf16_f32 %0, %1, %2" : "=v"(u2) : "v"(b[0]), "v"(b[1]));
    asm("v_cvt_pk_bf16_f32 %0, %1, %2" : "=v"(u3) : "v"(b[2]), "v"(b[3]));
    union { uint u[4]; short8 s; } r;
    r.u[0] = u0; r.u[1] = u1; r.u[2] = u2; r.u[3] = u3;
    return r.s;
}

static __device__ __forceinline__ void gload_lds16(const void* g, void* l) {
    __builtin_amdgcn_global_load_lds(
        (const __attribute__((address_space(1))) unsigned int*)g,
        (__attribute__((address_space(3))) unsigned int*)l, 16, 0, 0);
}
static __device__ __forceinline__ void gload_lds4(const void* g, void* l) {
    __builtin_amdgcn_global_load_lds(
        (const __attribute__((address_space(1))) unsigned int*)g,
        (__attribute__((address_space(3))) unsigned int*)l, 4, 0, 0);
}

// Pack U_w (g,h) f32 -> bf16 frag order, g-half-major:
// off = ((gh*NCH + ks)*GHF + fh)*1024B ; elem: g=(gh*GHF+fh)*16+(lane&15), h=ks*32+(lane>>4)*8+j
__global__ void pack_u(const float* __restrict__ Uw, ushort* __restrict__ Bp) {
    int idx = blockIdx.x * 256 + threadIdx.x;
    if (idx >= 2 * NCH * GHF * 64) return;
    int lane = idx & 63;
    int rem = idx >> 6;
    int fh = rem % GHF;
    int ks = (rem / GHF) % NCH;
    int gh = rem / (GHF * NCH);
    int g = (gh * GHF + fh) * 16 + (lane & 15);
    int h0 = ks * 32 + (lane >> 4) * 8;
    ushort v[8];
#pragma unroll
    for (int j = 0; j < 8; ++j) {
        int h = h0 + j;
        v[j] = (g < HH && h < HH) ? f2bf(Uw[g * HH + h]) : (ushort)0;
    }
    *reinterpret_cast<short8*>(Bp + (size_t)idx * 8) = *reinterpret_cast<const short8*>(v);
}

// Vx[b,n,g] = sum_h x[b,n,h]*Vw[g,h] + Vb[g] + 0.5*Ub[g]   (Ub folded)
__global__ void vx_kernel(const float* __restrict__ x, const float* __restrict__ Vw,
                          const float* __restrict__ Vb, const float* __restrict__ Ub,
                          float* __restrict__ Vx) {
    __shared__ float xs[HH];
    int row = blockIdx.x;
    const float* xr = x + (size_t)row * HH;
    for (int h = threadIdx.x; h < HH; h += 256) xs[h] = xr[h];
    __syncthreads();
    for (int g = threadIdx.x; g < HH; g += 256) {
        const float4* wr = reinterpret_cast<const float4*>(Vw + (size_t)g * HH);
        const float4* xv = reinterpret_cast<const float4*>(xs);
        float s0 = 0.f, s1 = 0.f, s2 = 0.f, s3 = 0.f;
#pragma unroll 5
        for (int k = 0; k < HH / 4; ++k) {
            float4 w = wr[k];
            float4 xx = xv[k];
            s0 += w.x * xx.x; s1 += w.y * xx.y; s2 += w.z * xx.z; s3 += w.w * xx.w;
        }
        Vx[(size_t)row * HH + g] = Vb[g] + 0.5f * Ub[g] + s0 + s1 + s2 + s3;
    }
}

// BM=64 x g-half, 256 thr (4 waves x 16 rows), BK=32, 10 chunks, 28 KB LDS,
// __launch_bounds__(256,4) -> 4 blocks/CU (16 waves). Stage-2-ahead schedule with
// CORRECT counted vmcnt: each phase issues exactly 6 loads/thread (B: 2x16B+2x4B,
// A: 2 float4), WAITV(6) retires only PRIOR chunks' loads, never the in-flight one.
// A: global->reg->cvt->ds_write bf16 frag layout. B: gload_lds DMA from L2.
__launch_bounds__(256, 4)
__global__ void gemm_kernel(const float* __restrict__ e, const ushort* __restrict__ Bp,
                            const float* __restrict__ Vx, float* __restrict__ out) {
    __shared__ __align__(16) ushort Alds[2][BM * 32];      // 2 x 4 KB (bf16 frags)
    __shared__ __align__(16) ushort Blds[2][GHF * 512];    // 2 x 10 KB
    const int tid = threadIdx.x;
    const int w = tid >> 6, l = tid & 63;
    const int r = l & 15, q = l >> 4;
    const int gh = blockIdx.x & 1;
    const int m0 = (blockIdx.x >> 1) * BM;
    const int arow = tid >> 2;            // 0..63: A row this thread stages
    const int acg = tid & 3;              // col-group (8 f32) within BK=32
    const float* rowp = e + (size_t)(m0 + arow) * HH;
    const int awidx = ((arow >> 4) * 64 + (arow & 15) + acg * 16) * 8;  // frag slot
    const char* bbase = (const char*)Bp + (size_t)gh * (NCH * GHF * 1024);

    float4v s0a, s0b, s1a, s1b;           // 2 rotating A reg sets

    float4v acc[GHF];
#pragma unroll
    for (int f = 0; f < GHF; ++f) acc[f] = (float4v){0.f, 0.f, 0.f, 0.f};

#define LOAD_A(K_, S_) do {                                                     \
        int c0_ = (K_) * 32 + acg * 8;                                          \
        const float* p0_ = (c0_ + 4 <= HH) ? rowp + c0_ : e;                    \
        const float* p1_ = (c0_ + 8 <= HH) ? rowp + c0_ + 4 : e;                \
        S_##a = *reinterpret_cast<const float4v*>(p0_);                         \
        S_##b = *reinterpret_cast<const float4v*>(p1_);                         \
    } while (0)

#define WRITE_A(K_, S_, P_) do {                                                \
        short8 w_ = pack8_cvt(S_##a, S_##b);                                    \
        if ((K_) == 9) {                                                        \
            _Pragma("unroll")                                                   \
            for (int j_ = 0; j_ < 8; ++j_)                                      \
                if (288 + acg * 8 + j_ >= HH) w_[j_] = 0;                       \
        }                                                                       \
        *reinterpret_cast<short8*>(&Alds[P_][awidx]) = w_;                      \
    } while (0)

    // B chunk (10 KB): 2x16B rounds + 2x4B rounds -> uniform 4 vmcnt entries/thread
#define ISSUE_B(K_, P_) do {                                                    \
        const char* bs_ = bbase + (size_t)(K_) * (GHF * 1024);                  \
        char* bd_ = (char*)&Blds[P_][0];                                        \
        gload_lds16(bs_ + tid * 16,        bd_ + tid * 16);                     \
        gload_lds16(bs_ + 4096 + tid * 16, bd_ + 4096 + tid * 16);              \
        gload_lds4(bs_ + 8192 + w * 512 + l * 4,       bd_ + 8192 + w * 512 + l * 4); \
        gload_lds4(bs_ + 8448 + w * 512 + l * 4,       bd_ + 8448 + w * 512 + l * 4); \
    } while (0)

#define COMPUTE(P_) do {                                                        \
        short8 fa_ = *reinterpret_cast<const short8*>(&Alds[P_][(w * 64 + l) * 8]); \
        const ushort* bb_ = &Blds[P_][l * 8];                                   \
        _Pragma("unroll")                                                       \
        for (int f_ = 0; f_ < GHF; ++f_) {                                      \
            short8 bf_ = *reinterpret_cast<const short8*>(bb_ + f_ * 512);      \
            acc[f_] = __builtin_amdgcn_mfma_f32_16x16x32_bf16(bf_, fa_, acc[f_], 0, 0, 0); \
        }                                                                       \
    } while (0)

#define WAITV(N_) do {                                                          \
        __builtin_amdgcn_sched_barrier(0);                                      \
        asm volatile("s_waitcnt vmcnt(" #N_ ")" ::: "memory");                  \
        __builtin_amdgcn_sched_barrier(0);                                      \
    } while (0)

#define BARX() do {                                                             \
        asm volatile("s_waitcnt lgkmcnt(0)" ::: "memory");                      \
        __builtin_amdgcn_s_barrier();                                           \
        __builtin_amdgcn_sched_barrier(0);                                      \
    } while (0)

    // ---- prologue: chunks 0,1 staged; WAITV(6) retires chunk 0, leaves chunk 1 ----
    LOAD_A(0, s0); ISSUE_B(0, 0);
    LOAD_A(1, s1); ISSUE_B(1, 1);
    WRITE_A(0, s0, 0);          // compiler-guarded wait on s0's loads only
    WAITV(6); BARX();

    // ---- steady phases i=0..7: C(i); BAR; issue chunk i+2; write A(i+1); WAITV(6) ----
#define PHASE(I_, PC_, PN_, SLD_, SWR_) do {                                    \
        COMPUTE(PC_); BARX();                                                   \
        ISSUE_B((I_) + 2, PC_); LOAD_A((I_) + 2, SLD_);                         \
        WRITE_A((I_) + 1, SWR_, PN_);                                           \
        WAITV(6); BARX();                                                       \
    } while (0)

    PHASE(0, 0, 1, s0, s1);
    PHASE(1, 1, 0, s1, s0);
    PHASE(2, 0, 1, s0, s1);
    PHASE(3, 1, 0, s1, s0);
    PHASE(4, 0, 1, s0, s1);
    PHASE(5, 1, 0, s1, s0);
    PHASE(6, 0, 1, s0, s1);
    PHASE(7, 1, 0, s1, s0);

    // tail: chunks 8,9 already staged/in-flight
    COMPUTE(0); BARX();
    WRITE_A(9, s1, 1);
    WAITV(0); BARX();
    COMPUTE(1);

    // ---- epilogue: out[m][g] = acc + Vx'[i][g] + Vx'[j][g] (Ub folded in Vx') ----
    {
        const int mrow = m0 + w * 16 + r;
        int j = mrow % NN;
        int ti = mrow / NN;       // b*NN + i
        int b = ti / NN;
        const float* vi = Vx + (size_t)ti * HH;
        const float* vj = Vx + (size_t)(b * NN + j) * HH;
        float* orow = out + (size_t)mrow * HH;
        const int gbase = gh * (GHF * 16);
#pragma unroll
        for (int f = 0; f < GHF; ++f) {
            int g0 = gbase + f * 16 + q * 4;
            if (g0 + 4 <= HH) {
                float4v vi4 = *reinterpret_cast<const float4v*>(vi + g0);
                float4v vj4 = *reinterpret_cast<const float4v*>(vj + g0);
                *reinterpret_cast<float4v*>(orow + g0) = acc[f] + vi4 + vj4;
            }
        }
    }
#undef LOAD_A
#undef WRITE_A
#undef ISSUE_B
#undef COMPUTE
#undef WAITV
#undef BARX
#undef PHASE
}

extern "C" void kernel_launch(void* const* d_in, const int* in_sizes, int n_in,
                              void* d_out, int out_size, void* d_ws, size_t ws_size,
                              hipStream_t stream) {
    const float* x  = (const float*)d_in[0];
    const float* e  = (const float*)d_in[1];
    const float* Uw = (const float*)d_in[2];
    const float* Ub = (const float*)d_in[3];
    const float* Vw = (const float*)d_in[4];
    const float* Vb = (const float*)d_in[5];
    float* out = (float*)d_out;

    ushort* Bp = (ushort*)d_ws;                              // 204,800 B (frag-packed bf16 U_w)
    float*  Vx = (float*)((char*)d_ws + 204800);             // 960,000 B

    pack_u<<<50, 256, 0, stream>>>(Uw, Bp);
    vx_kernel<<<BB * NN, 256, 0, stream>>>(x, Vw, Vb, Ub, Vx);
    // 2500 m-tiles x 2 g-halves; twin blocks (same e rows) adjacent for L3 reuse
    gemm_kernel<<<5000, 256, 0, stream>>>(e, Bp, Vx, out);
}

// Round 16
// 160.878 us; speedup vs baseline: 1.3554x; 1.1542x over previous
//
#include <hip/hip_runtime.h>
#include <hip/hip_bf16.h>

#define BB 4
#define NN 200
#define HH 300
#define NCH 10            // k-steps of 32 (K padded to 320)
#define GF 20             // g-frags of 16 (G padded to 320; frag 19 zero)
#define BM 64             // rows per block (16 per wave)

typedef __attribute__((ext_vector_type(8))) short short8;
typedef __attribute__((ext_vector_type(4))) float float4v;

static __device__ __forceinline__ ushort f2bf(float x) {
    union { float f; uint u; } v; v.f = x;
    uint r = v.u + 0x7FFFu + ((v.u >> 16) & 1u);  // RNE
    return (ushort)(r >> 16);
}

// 8 f32 -> 8 bf16 (RNE) via v_cvt_pk_bf16_f32
static __device__ __forceinline__ short8 pack8_cvt(float4v a, float4v b) {
    uint u0, u1, u2, u3;
    asm("v_cvt_pk_bf16_f32 %0, %1, %2" : "=v"(u0) : "v"(a[0]), "v"(a[1]));
    asm("v_cvt_pk_bf16_f32 %0, %1, %2" : "=v"(u1) : "v"(a[2]), "v"(a[3]));
    asm("v_cvt_pk_bf16_f32 %0, %1, %2" : "=v"(u2) : "v"(b[0]), "v"(b[1]));
    asm("v_cvt_pk_bf16_f32 %0, %1, %2" : "=v"(u3) : "v"(b[2]), "v"(b[3]));
    union { uint u[4]; short8 s; } r;
    r.u[0] = u0; r.u[1] = u1; r.u[2] = u2; r.u[3] = u3;
    return r.s;
}

static __device__ __forceinline__ void gload_lds16(const void* g, void* l) {
    __builtin_amdgcn_global_load_lds(
        (const __attribute__((address_space(1))) unsigned int*)g,
        (__attribute__((address_space(3))) unsigned int*)l, 16, 0, 0);
}

// Pack U_w (g,h) f32 -> bf16 in MFMA frag order (ks-major, full G):
// Bp[((ks*GF+gf)*64 + lane)*8 + j] = Uw[g=gf*16+(lane&15)][h=ks*32+(lane>>4)*8+j], 0 if OOB
__global__ void pack_u(const float* __restrict__ Uw, ushort* __restrict__ Bp) {
    int idx = blockIdx.x * 256 + threadIdx.x;
    if (idx >= NCH * GF * 64) return;
    int lane = idx & 63;
    int kg = idx >> 6;
    int gf = kg % GF, ks = kg / GF;
    int g = gf * 16 + (lane & 15);
    int h0 = ks * 32 + (lane >> 4) * 8;
    ushort v[8];
#pragma unroll
    for (int j = 0; j < 8; ++j) {
        int h = h0 + j;
        v[j] = (g < HH && h < HH) ? f2bf(Uw[g * HH + h]) : (ushort)0;
    }
    *reinterpret_cast<short8*>(Bp + (size_t)idx * 8) = *reinterpret_cast<const short8*>(v);
}

// Vx[b,n,g] = sum_h x[b,n,h]*Vw[g,h] + Vb[g] + 0.5*Ub[g]   (Ub folded)
__global__ void vx_kernel(const float* __restrict__ x, const float* __restrict__ Vw,
                          const float* __restrict__ Vb, const float* __restrict__ Ub,
                          float* __restrict__ Vx) {
    __shared__ float xs[HH];
    int row = blockIdx.x;
    const float* xr = x + (size_t)row * HH;
    for (int h = threadIdx.x; h < HH; h += 256) xs[h] = xr[h];
    __syncthreads();
    for (int g = threadIdx.x; g < HH; g += 256) {
        const float4* wr = reinterpret_cast<const float4*>(Vw + (size_t)g * HH);
        const float4* xv = reinterpret_cast<const float4*>(xs);
        float s0 = 0.f, s1 = 0.f, s2 = 0.f, s3 = 0.f;
#pragma unroll 5
        for (int k = 0; k < HH / 4; ++k) {
            float4 w = wr[k];
            float4 xx = xv[k];
            s0 += w.x * xx.x; s1 += w.y * xx.y; s2 += w.z * xx.z; s3 += w.w * xx.w;
        }
        Vx[(size_t)row * HH + g] = Vb[g] + 0.5f * Ub[g] + s0 + s1 + s2 + s3;
    }
}

// T3 minimal template, one barrier per phase. BM=64 x full G, 256 thr / 4 waves.
// A is WAVE-PRIVATE -> no LDS for A: per-lane f32 loads (2x float4), prefetched one
// phase ahead in alternating reg sets, cvt in-reg. Only B staged: double-buffered
// 2x20 KB via gload_lds. Phase: {STAGE_B(t+1,P^1); compute(P) [20 MFMA + 20 ds_read];
// sched_barrier; vmcnt(0); s_barrier}. LDS 40 KB, (256,3) -> 3 blocks/CU.
__launch_bounds__(256, 3)
__global__ void gemm_kernel(const float* __restrict__ e, const ushort* __restrict__ Bp,
                            const float* __restrict__ Vx, float* __restrict__ out) {
    __shared__ __align__(16) ushort Blds[2][GF * 512];    // 2 x 20 KB
    const int tid = threadIdx.x;
    const int w = tid >> 6, l = tid & 63;
    const int r = l & 15, q = l >> 4;
    const int m0 = blockIdx.x * BM;
    const float* rowp = e + (size_t)(m0 + w * 16 + r) * HH;   // lane-private A row

    float4v acc[GF];
#pragma unroll
    for (int f = 0; f < GF; ++f) acc[f] = (float4v){0.f, 0.f, 0.f, 0.f};

    float4v e0a, e0b, e1a, e1b;   // alternating A reg sets (even/odd phase)

#define LOAD_A(K_, S_) do {                                                     \
        int c0_ = (K_) * 32 + q * 8;                                            \
        const float* p0_ = (c0_ + 4 <= HH) ? rowp + c0_ : e;                    \
        const float* p1_ = (c0_ + 8 <= HH) ? rowp + c0_ + 4 : e;                \
        S_##a = *reinterpret_cast<const float4v*>(p0_);                         \
        S_##b = *reinterpret_cast<const float4v*>(p1_);                         \
    } while (0)

    // B chunk (20 KB): 5 x 4 KB rounds, fully linear, uniform 5 loads/thread
#define STAGE_B(K_, P_) do {                                                    \
        const char* bs_ = (const char*)Bp + (size_t)(K_) * (GF * 1024);         \
        char* bd_ = (char*)&Blds[P_][0];                                        \
        _Pragma("unroll")                                                       \
        for (int rd_ = 0; rd_ < 5; ++rd_)                                       \
            gload_lds16(bs_ + rd_ * 4096 + tid * 16, bd_ + rd_ * 4096 + tid * 16); \
    } while (0)

    // compute phase K_ from Blds[P_]: fa = cvt(regs), 20 MFMA (swapped operands:
    // acc reg-index = g quad, lane&15 = row)
#define COMPUTE(K_, P_, S_) do {                                                \
        short8 fa_ = pack8_cvt(S_##a, S_##b);                                   \
        if ((K_) == 9) {                                                        \
            int c0_ = 288 + q * 8;                                              \
            _Pragma("unroll")                                                   \
            for (int j_ = 0; j_ < 8; ++j_)                                      \
                if (c0_ + j_ >= HH) fa_[j_] = 0;                                \
        }                                                                       \
        const ushort* bb_ = &Blds[P_][l * 8];                                   \
        _Pragma("unroll")                                                       \
        for (int f_ = 0; f_ < GF; ++f_) {                                       \
            short8 bf_ = *reinterpret_cast<const short8*>(bb_ + f_ * 512);      \
            acc[f_] = __builtin_amdgcn_mfma_f32_16x16x32_bf16(bf_, fa_, acc[f_], 0, 0, 0); \
        }                                                                       \
    } while (0)

#define ENDPHASE() do {                                                         \
        __builtin_amdgcn_sched_barrier(0);                                      \
        asm volatile("s_waitcnt vmcnt(0)" ::: "memory");                        \
        __builtin_amdgcn_s_barrier();                                           \
        __builtin_amdgcn_sched_barrier(0);                                      \
    } while (0)

    // prologue: stage chunk 0, load A(0); one arrival wait
    STAGE_B(0, 0); LOAD_A(0, e0);
    ENDPHASE();

    // phases t=0..9: stage t+1 into P^1 + prefetch A(t+1), compute t from P
#define PHASE(T_, P_, SC_, SN_) do {                                            \
        if ((T_) < 9) { STAGE_B((T_) + 1, (P_) ^ 1); LOAD_A((T_) + 1, SN_); }   \
        COMPUTE(T_, P_, SC_);                                                   \
        if ((T_) < 9) ENDPHASE();                                               \
    } while (0)

    PHASE(0, 0, e0, e1);
    PHASE(1, 1, e1, e0);
    PHASE(2, 0, e0, e1);
    PHASE(3, 1, e1, e0);
    PHASE(4, 0, e0, e1);
    PHASE(5, 1, e1, e0);
    PHASE(6, 0, e0, e1);
    PHASE(7, 1, e1, e0);
    PHASE(8, 0, e0, e1);
    PHASE(9, 1, e1, e0);

    // ---- epilogue: out[m][g] = acc + Vx'[i][g] + Vx'[j][g]  (Ub folded in Vx') ----
    {
        const int m = m0 + w * 16 + r;
        int j = m % NN;
        int ti = m / NN;        // b*NN + i
        int b = ti / NN;
        const float* vi = Vx + (size_t)ti * HH;
        const float* vj = Vx + (size_t)(b * NN + j) * HH;
        float* orow = out + (size_t)m * HH;
#pragma unroll
        for (int f = 0; f < GF - 1; ++f) {
            int g0 = f * 16 + q * 4;
            if (g0 + 4 <= HH) {
                float4v vi4 = *reinterpret_cast<const float4v*>(vi + g0);
                float4v vj4 = *reinterpret_cast<const float4v*>(vj + g0);
                *reinterpret_cast<float4v*>(orow + g0) = acc[f] + vi4 + vj4;
            }
        }
    }
#undef LOAD_A
#undef STAGE_B
#undef COMPUTE
#undef ENDPHASE
#undef PHASE
}

extern "C" void kernel_launch(void* const* d_in, const int* in_sizes, int n_in,
                              void* d_out, int out_size, void* d_ws, size_t ws_size,
                              hipStream_t stream) {
    const float* x  = (const float*)d_in[0];
    const float* e  = (const float*)d_in[1];
    const float* Uw = (const float*)d_in[2];
    const float* Ub = (const float*)d_in[3];
    const float* Vw = (const float*)d_in[4];
    const float* Vb = (const float*)d_in[5];
    float* out = (float*)d_out;

    ushort* Bp = (ushort*)d_ws;                              // 204,800 B (frag-packed bf16 U_w)
    float*  Vx = (float*)((char*)d_ws + 204800);             // 960,000 B

    pack_u<<<50, 256, 0, stream>>>(Uw, Bp);
    vx_kernel<<<BB * NN, 256, 0, stream>>>(x, Vw, Vb, Ub, Vx);
    gemm_kernel<<<160000 / BM, 256, 0, stream>>>(e, Bp, Vx, out);
}

// Round 17
// 151.594 us; speedup vs baseline: 1.4384x; 1.0612x over previous
//
#include <hip/hip_runtime.h>
#include <hip/hip_bf16.h>

#define BB 4
#define NN 200
#define HH 300
#define GF 20             // g-frags of 16 (G padded to 320; frag 19 zero)
#define BM 64             // rows per block (16 per wave)

typedef __attribute__((ext_vector_type(8))) short short8;
typedef __attribute__((ext_vector_type(4))) float float4v;

static __device__ __forceinline__ ushort f2bf(float x) {
    union { float f; uint u; } v; v.f = x;
    uint r = v.u + 0x7FFFu + ((v.u >> 16) & 1u);  // RNE
    return (ushort)(r >> 16);
}

// 8 f32 -> 8 bf16 (RNE) via v_cvt_pk_bf16_f32
static __device__ __forceinline__ short8 pack8_cvt(float4v a, float4v b) {
    uint u0, u1, u2, u3;
    asm("v_cvt_pk_bf16_f32 %0, %1, %2" : "=v"(u0) : "v"(a[0]), "v"(a[1]));
    asm("v_cvt_pk_bf16_f32 %0, %1, %2" : "=v"(u1) : "v"(a[2]), "v"(a[3]));
    asm("v_cvt_pk_bf16_f32 %0, %1, %2" : "=v"(u2) : "v"(b[0]), "v"(b[1]));
    asm("v_cvt_pk_bf16_f32 %0, %1, %2" : "=v"(u3) : "v"(b[2]), "v"(b[3]));
    union { uint u[4]; short8 s; } r;
    r.u[0] = u0; r.u[1] = u1; r.u[2] = u2; r.u[3] = u3;
    return r.s;
}

static __device__ __forceinline__ void gload_lds16(const void* g, void* l) {
    __builtin_amdgcn_global_load_lds(
        (const __attribute__((address_space(1))) unsigned int*)g,
        (__attribute__((address_space(3))) unsigned int*)l, 16, 0, 0);
}

// Pack U_w (g,h) f32 -> bf16 in MFMA frag order (ks-major, full G):
// Bp[((ks*GF+gf)*64 + lane)*8 + j] = Uw[g=gf*16+(lane&15)][h=ks*32+(lane>>4)*8+j], 0 if OOB
__global__ void pack_u(const float* __restrict__ Uw, ushort* __restrict__ Bp) {
    int idx = blockIdx.x * 256 + threadIdx.x;
    if (idx >= 10 * GF * 64) return;
    int lane = idx & 63;
    int kg = idx >> 6;
    int gf = kg % GF, ks = kg / GF;
    int g = gf * 16 + (lane & 15);
    int h0 = ks * 32 + (lane >> 4) * 8;
    ushort v[8];
#pragma unroll
    for (int j = 0; j < 8; ++j) {
        int h = h0 + j;
        v[j] = (g < HH && h < HH) ? f2bf(Uw[g * HH + h]) : (ushort)0;
    }
    *reinterpret_cast<short8*>(Bp + (size_t)idx * 8) = *reinterpret_cast<const short8*>(v);
}

// Vx[b,n,g] = sum_h x[b,n,h]*Vw[g,h] + Vb[g] + 0.5*Ub[g]   (Ub folded)
__global__ void vx_kernel(const float* __restrict__ x, const float* __restrict__ Vw,
                          const float* __restrict__ Vb, const float* __restrict__ Ub,
                          float* __restrict__ Vx) {
    __shared__ float xs[HH];
    int row = blockIdx.x;
    const float* xr = x + (size_t)row * HH;
    for (int h = threadIdx.x; h < HH; h += 256) xs[h] = xr[h];
    __syncthreads();
    for (int g = threadIdx.x; g < HH; g += 256) {
        const float4* wr = reinterpret_cast<const float4*>(Vw + (size_t)g * HH);
        const float4* xv = reinterpret_cast<const float4*>(xs);
        float s0 = 0.f, s1 = 0.f, s2 = 0.f, s3 = 0.f;
#pragma unroll 5
        for (int k = 0; k < HH / 4; ++k) {
            float4 w = wr[k];
            float4 xx = xv[k];
            s0 += w.x * xx.x; s1 += w.y * xx.y; s2 += w.z * xx.z; s3 += w.w * xx.w;
        }
        Vx[(size_t)row * HH + g] = Vb[g] + 0.5f * Ub[g] + s0 + s1 + s2 + s3;
    }
}

// BM=64 x full G, 256 thr / 4 waves, BK=64 -> 5 phases. A wave-private (no LDS):
// per-lane f32 loads, 2 rotating reg sets, cvt in-reg. B double-buffered 2x40 KB
// via gload_lds, staged TWO chunks ahead; WAITV(14) retires exactly the previous
// chunk's 14 loads (10 B + 4 A), so the in-flight chunk rides across barriers.
// Phase: {COMPUTE(P); BAR; STAGE(t+2 -> P); WAITV(14); BAR}. (256,2), 2 blocks/CU.
__launch_bounds__(256, 2)
__global__ void gemm_kernel(const float* __restrict__ e, const ushort* __restrict__ Bp,
                            const float* __restrict__ Vx, float* __restrict__ out) {
    __shared__ __align__(16) ushort Blds[2][20480];   // 2 x 40 KB (2 sub-ks x 20 frags)
    const int tid = threadIdx.x;
    const int w = tid >> 6, l = tid & 63;
    const int r = l & 15, q = l >> 4;
    const int m0 = blockIdx.x * BM;
    const float* rowp = e + (size_t)(m0 + w * 16 + r) * HH;   // lane-private A row

    float4v acc[GF];
#pragma unroll
    for (int f = 0; f < GF; ++f) acc[f] = (float4v){0.f, 0.f, 0.f, 0.f};

    // two rotating A reg sets, 4 float4 each (sub-ks 0: a0,a1 ; sub-ks 1: b0,b1)
    float4v s0a0, s0a1, s0b0, s0b1, s1a0, s1a1, s1b0, s1b1;

#define LOAD_A(KC_, S_) do {                                                    \
        int ca_ = (KC_) * 64 + q * 8;                                           \
        int cb_ = ca_ + 32;                                                     \
        const float* pa0_ = (ca_ + 4 <= HH) ? rowp + ca_ : e;                   \
        const float* pa1_ = (ca_ + 8 <= HH) ? rowp + ca_ + 4 : e;               \
        const float* pb0_ = (cb_ + 4 <= HH) ? rowp + cb_ : e;                   \
        const float* pb1_ = (cb_ + 8 <= HH) ? rowp + cb_ + 4 : e;               \
        S_##a0 = *reinterpret_cast<const float4v*>(pa0_);                       \
        S_##a1 = *reinterpret_cast<const float4v*>(pa1_);                       \
        S_##b0 = *reinterpret_cast<const float4v*>(pb0_);                       \
        S_##b1 = *reinterpret_cast<const float4v*>(pb1_);                       \
    } while (0)

    // B chunk (40 KB = ks 2KC_, 2KC_+1): 10 x 4 KB linear rounds -> 10 loads/thread
#define STAGE_B(KC_, P_) do {                                                   \
        const char* bs_ = (const char*)Bp + (size_t)(KC_) * 40960;              \
        char* bd_ = (char*)&Blds[P_][0];                                        \
        _Pragma("unroll")                                                       \
        for (int rd_ = 0; rd_ < 10; ++rd_)                                      \
            gload_lds16(bs_ + rd_ * 4096 + tid * 16, bd_ + rd_ * 4096 + tid * 16); \
    } while (0)

    // compute chunk KC_ from Blds[P_]: 2 sub-ks x 20 frags = 40 MFMA
#define COMPUTE(KC_, P_, S_) do {                                               \
        short8 fa0_ = pack8_cvt(S_##a0, S_##a1);                                \
        short8 fa1_ = pack8_cvt(S_##b0, S_##b1);                                \
        if ((KC_) == 4) {   /* ks=9: zero cols >= 300 (cols 288+q*8+j) */       \
            int c0_ = 288 + q * 8;                                              \
            _Pragma("unroll")                                                   \
            for (int j_ = 0; j_ < 8; ++j_)                                      \
                if (c0_ + j_ >= HH) fa1_[j_] = 0;                               \
        }                                                                       \
        const ushort* bb_ = &Blds[P_][l * 8];                                   \
        _Pragma("unroll")                                                       \
        for (int f_ = 0; f_ < GF; ++f_) {                                       \
            short8 bf_ = *reinterpret_cast<const short8*>(bb_ + f_ * 512);      \
            acc[f_] = __builtin_amdgcn_mfma_f32_16x16x32_bf16(bf_, fa0_, acc[f_], 0, 0, 0); \
        }                                                                       \
        _Pragma("unroll")                                                       \
        for (int f_ = 0; f_ < GF; ++f_) {                                       \
            short8 bf_ = *reinterpret_cast<const short8*>(bb_ + 10240 + f_ * 512); \
            acc[f_] = __builtin_amdgcn_mfma_f32_16x16x32_bf16(bf_, fa1_, acc[f_], 0, 0, 0); \
        }                                                                       \
    } while (0)

#define WAITV(N_) do {                                                          \
        __builtin_amdgcn_sched_barrier(0);                                      \
        asm volatile("s_waitcnt vmcnt(" #N_ ")" ::: "memory");                  \
        __builtin_amdgcn_sched_barrier(0);                                      \
    } while (0)

#define BARX() do {                                                             \
        asm volatile("s_waitcnt lgkmcnt(0)" ::: "memory");                      \
        __builtin_amdgcn_s_barrier();                                           \
        __builtin_amdgcn_sched_barrier(0);                                      \
    } while (0)

    // ---- prologue: chunks 0,1 in flight; retire chunk 0 (B0+A0 = first 14) ----
    STAGE_B(0, 0); LOAD_A(0, s0);
    STAGE_B(1, 1); LOAD_A(1, s1);
    WAITV(14); BARX();

    // ---- 5 phases, stage-2-ahead ----
    // t=0 (P=0): compute 0; stage 2 -> buf0
    COMPUTE(0, 0, s0); BARX();
    STAGE_B(2, 0); LOAD_A(2, s0); WAITV(14); BARX();
    // t=1 (P=1): compute 1; stage 3 -> buf1
    COMPUTE(1, 1, s1); BARX();
    STAGE_B(3, 1); LOAD_A(3, s1); WAITV(14); BARX();
    // t=2 (P=0): compute 2; stage 4 -> buf0
    COMPUTE(2, 0, s0); BARX();
    STAGE_B(4, 0); LOAD_A(4, s0); WAITV(14); BARX();
    // t=3 (P=1): compute 3; drain chunk 4
    COMPUTE(3, 1, s1); BARX();
    WAITV(0); BARX();
    // t=4 (P=0): compute 4
    COMPUTE(4, 0, s0);

    // ---- epilogue: out[m][g] = acc + Vx'[i][g] + Vx'[j][g]  (Ub folded in Vx') ----
    {
        const int m = m0 + w * 16 + r;
        int j = m % NN;
        int ti = m / NN;        // b*NN + i
        int b = ti / NN;
        const float* vi = Vx + (size_t)ti * HH;
        const float* vj = Vx + (size_t)(b * NN + j) * HH;
        float* orow = out + (size_t)m * HH;
#pragma unroll
        for (int f = 0; f < GF - 1; ++f) {
            int g0 = f * 16 + q * 4;
            if (g0 + 4 <= HH) {
                float4v vi4 = *reinterpret_cast<const float4v*>(vi + g0);
                float4v vj4 = *reinterpret_cast<const float4v*>(vj + g0);
                *reinterpret_cast<float4v*>(orow + g0) = acc[f] + vi4 + vj4;
            }
        }
    }
#undef LOAD_A
#undef STAGE_B
#undef COMPUTE
#undef WAITV
#undef BARX
}

extern "C" void kernel_launch(void* const* d_in, const int* in_sizes, int n_in,
                              void* d_out, int out_size, void* d_ws, size_t ws_size,
                              hipStream_t stream) {
    const float* x  = (const float*)d_in[0];
    const float* e  = (const float*)d_in[1];
    const float* Uw = (const float*)d_in[2];
    const float* Ub = (const float*)d_in[3];
    const float* Vw = (const float*)d_in[4];
    const float* Vb = (const float*)d_in[5];
    float* out = (float*)d_out;

    ushort* Bp = (ushort*)d_ws;                              // 204,800 B (frag-packed bf16 U_w)
    float*  Vx = (float*)((char*)d_ws + 204800);             // 960,000 B

    pack_u<<<50, 256, 0, stream>>>(Uw, Bp);
    vx_kernel<<<BB * NN, 256, 0, stream>>>(x, Vw, Vb, Ub, Vx);
    gemm_kernel<<<160000 / BM, 256, 0, stream>>>(e, Bp, Vx, out);
}